// Round 1
// baseline (531.650 us; speedup 1.0000x reference)
//
#include <hip/hip_runtime.h>
#include <math.h>

#define H_DIM 4096
#define NE    64
#define TOPK  8
#define BM    64          // tokens per block
#define BK    128         // k-chunk staged in LDS
#define NTHREADS 512      // 8 waves
#define EPW   8           // experts per wave (8 waves * 8 = 64 experts)
#define XS_STRIDE (BK + 4)  // 132 floats: (lane*33 + g) % 8 spreads bank-quads

__global__ __launch_bounds__(NTHREADS, 1)
void gemm_logits_kernel(const float* __restrict__ x, const float* __restrict__ W,
                        float* __restrict__ logits)
{
    // double-buffered x tile: 2 * 64 * 132 * 4B = 67.6 KB
    __shared__ float xs[2][BM][XS_STRIDE];

    const int tid  = threadIdx.x;
    const int lane = tid & 63;
    const int wave = tid >> 6;
    const int row0 = blockIdx.x * BM;
    // wave-uniform expert base -> lets the compiler scalarize W loads
    const int ebase = __builtin_amdgcn_readfirstlane(wave * EPW);

    // staging assignment: 512 threads cover 64 rows x 32 granules (x4 passes)
    const int sm = tid >> 3;   // 0..63 token row
    const int sg = tid & 7;    // granule group 0..7

    const float* xrow = x + (size_t)(row0 + sm) * H_DIM;

    float acc[EPW];
#pragma unroll
    for (int e = 0; e < EPW; ++e) acc[e] = 0.0f;

    // prologue: stage chunk 0 into buffer 0
    {
        float4 v[4];
#pragma unroll
        for (int p = 0; p < 4; ++p)
            v[p] = *(const float4*)(xrow + (sg + 8 * p) * 4);
#pragma unroll
        for (int p = 0; p < 4; ++p)
            *(float4*)&xs[0][sm][(sg + 8 * p) * 4] = v[p];
    }
    __syncthreads();

    for (int kc = 0; kc < H_DIM; kc += BK) {
        const int buf = (kc / BK) & 1;
        const bool has_next = (kc + BK) < H_DIM;

        // (a) issue next chunk's global loads early (hide HBM latency under compute)
        float4 pref[4];
        if (has_next) {
#pragma unroll
            for (int p = 0; p < 4; ++p)
                pref[p] = *(const float4*)(xrow + kc + BK + (sg + 8 * p) * 4);
        }

        // (b) compute current chunk; per-chunk accumulators keep fp32 error ~1e-6
        float cacc[EPW];
#pragma unroll
        for (int e = 0; e < EPW; ++e) cacc[e] = 0.0f;

#pragma unroll 8
        for (int k4 = 0; k4 < BK; k4 += 4) {
            const float4 xv = *(const float4*)&xs[buf][lane][k4];
#pragma unroll
            for (int e = 0; e < EPW; ++e) {
                const float4 wv = *(const float4*)(W + (size_t)(ebase + e) * H_DIM + kc + k4);
                cacc[e] = fmaf(xv.x, wv.x, cacc[e]);
                cacc[e] = fmaf(xv.y, wv.y, cacc[e]);
                cacc[e] = fmaf(xv.z, wv.z, cacc[e]);
                cacc[e] = fmaf(xv.w, wv.w, cacc[e]);
            }
        }
#pragma unroll
        for (int e = 0; e < EPW; ++e) acc[e] += cacc[e];

        // (c) write next chunk into the other buffer, (d) barrier
        if (has_next) {
#pragma unroll
            for (int p = 0; p < 4; ++p)
                *(float4*)&xs[buf ^ 1][sm][(sg + 8 * p) * 4] = pref[p];
        }
        __syncthreads();
    }

    // epilogue: logits[row0+lane][ebase .. ebase+7]
    float* lo = logits + (size_t)(row0 + lane) * NE + ebase;
    *(float4*)lo       = make_float4(acc[0], acc[1], acc[2], acc[3]);
    *(float4*)(lo + 4) = make_float4(acc[4], acc[5], acc[6], acc[7]);
}

__global__ __launch_bounds__(256, 1)
void router_kernel(const float* __restrict__ logits, float* __restrict__ scores,
                   float* __restrict__ wts, float* __restrict__ inds, int N)
{
    const int token = blockIdx.x * 4 + (threadIdx.x >> 6);
    const int lane  = threadIdx.x & 63;
    if (token >= N) return;

    const float l = logits[(size_t)token * NE + lane];

    // wave softmax (lane = expert)
    float m = l;
#pragma unroll
    for (int off = 32; off >= 1; off >>= 1)
        m = fmaxf(m, __shfl_xor(m, off, 64));
    const float p = expf(l - m);
    float s = p;
#pragma unroll
    for (int off = 32; off >= 1; off >>= 1)
        s += __shfl_xor(s, off, 64);
    const float sc = p / s;
    scores[(size_t)token * NE + lane] = sc;

    // iterative top-8 argmax, tie-break to LOWER index (matches lax.top_k)
    float cur = sc;
    float tv[TOPK];
    int   ti[TOPK];
    float sum8 = 0.0f;
#pragma unroll
    for (int k = 0; k < TOPK; ++k) {
        float v = cur; int i = lane;
#pragma unroll
        for (int off = 32; off >= 1; off >>= 1) {
            float ov = __shfl_xor(v, off, 64);
            int   oi = __shfl_xor(i, off, 64);
            if (ov > v || (ov == v && oi < i)) { v = ov; i = oi; }
        }
        tv[k] = v; ti[k] = i;
        sum8 += v;
        if (lane == i) cur = -1.0f;  // scores > 0, so -1 masks
    }

    if (lane == 0) {
#pragma unroll
        for (int k = 0; k < TOPK; ++k) {
            wts[(size_t)token * TOPK + k]  = tv[k] / sum8;   // L1 renorm (all positive)
            inds[(size_t)token * TOPK + k] = (float)ti[k];   // whole d_out read as f32
        }
    }
}

extern "C" void kernel_launch(void* const* d_in, const int* in_sizes, int n_in,
                              void* d_out, int out_size, void* d_ws, size_t ws_size,
                              hipStream_t stream)
{
    const float* x = (const float*)d_in[0];
    const float* W = (const float*)d_in[1];
    const int N = in_sizes[0] / H_DIM;   // 16384

    float* out    = (float*)d_out;
    float* scores = out;                              // [N,64]
    float* logits = out + (size_t)N * NE;             // [N,64]
    float* wts    = out + (size_t)2 * N * NE;         // [N,8]
    float* inds   = wts + (size_t)N * TOPK;           // [N,8] (as float)

    gemm_logits_kernel<<<N / BM, NTHREADS, 0, stream>>>(x, W, logits);
    router_kernel<<<(N + 3) / 4, 256, 0, stream>>>(logits, scores, wts, inds, N);
}

// Round 3
// 117.695 us; speedup vs baseline: 4.5172x; 4.5172x over previous
//
#include <hip/hip_runtime.h>
#include <math.h>

#define H_DIM  4096
#define NE     64
#define TOPK   8
#define KSTEPS 128                // H_DIM / 32
#define WTERM  (NE * H_DIM)       // 262144 elems per packed-W term plane
#define LO_SCALE 2048.0f          // 2^11
#define INV_LO_SCALE (1.0f / 2048.0f)

using f16x8 = __attribute__((ext_vector_type(8))) _Float16;
using f32x4 = __attribute__((ext_vector_type(4))) float;

// ---------------- W pre-pack: fp16 2-term split in MFMA B-fragment order ----
// pk[term][kstep][NF][lane][8]: lane = g*16 + (e&15), slot j -> k = kstep*32 + g*8 + j
__global__ __launch_bounds__(256, 1)
void pack_w_kernel(const float* __restrict__ W, _Float16* __restrict__ pk)
{
    int id = blockIdx.x * 256 + threadIdx.x;          // 0 .. 262143
    int e = id >> 12;                                  // / 4096
    int k = id & 4095;
    float f = W[id];
    _Float16 h = (_Float16)f;                          // RNE
    float r = (f - (float)h) * LO_SCALE;               // exact residual, scaled to fp16-normal range
    _Float16 l = (_Float16)r;
    int NF = e >> 4, rr = e & 15;
    int kstep = k >> 5, g = (k >> 3) & 3, j = k & 7;
    int lane = g * 16 + rr;
    size_t idx = (size_t)(kstep * 4 + NF) * 512 + (size_t)lane * 8 + j;
    pk[idx] = h;
    pk[WTERM + idx] = l;
}

// ---------------- main GEMM: logits = x (16384x4096) . W^T (4096x64) --------
// wave = 32 tokens x 32 experts; block = 2 waves (expert halves); grid = 512
__global__ __launch_bounds__(128, 1)
void moe_logits_mfma(const float* __restrict__ x, const _Float16* __restrict__ pk,
                     float* __restrict__ logits)
{
    const int lane = threadIdx.x & 63;
    const int eh   = threadIdx.x >> 6;      // expert half 0/1
    const int row0 = blockIdx.x * 32;
    const int g = lane >> 4, r = lane & 15;

    const float* xp0 = x + (size_t)(row0 + r) * H_DIM + g * 8;       // m-frag 0
    const float* xp1 = xp0 + (size_t)16 * H_DIM;                      // m-frag 1
    const _Float16* wp = pk + (size_t)(eh * 2) * 512 + (size_t)lane * 8;

    f32x4 acc[2][2], accL[2][2];
#pragma unroll
    for (int m = 0; m < 2; ++m)
#pragma unroll
        for (int n = 0; n < 2; ++n) {
            acc[m][n]  = (f32x4)0.0f;
            accL[m][n] = (f32x4)0.0f;
        }

    f32x4 xa[2][2][2];   // [buf][mfrag][half]
    f16x8 wa[2][2][2];   // [buf][term][nf]

#define LOADX(ks, b)                                                     \
    do {                                                                 \
        xa[b][0][0] = *(const f32x4*)(xp0 + (ks) * 32);                  \
        xa[b][0][1] = *(const f32x4*)(xp0 + (ks) * 32 + 4);              \
        xa[b][1][0] = *(const f32x4*)(xp1 + (ks) * 32);                  \
        xa[b][1][1] = *(const f32x4*)(xp1 + (ks) * 32 + 4);              \
    } while (0)

#define LOADW(ks, b)                                                     \
    do {                                                                 \
        const _Float16* p_ = wp + (size_t)(ks) * 2048;                   \
        wa[b][0][0] = *(const f16x8*)(p_);                               \
        wa[b][0][1] = *(const f16x8*)(p_ + 512);                         \
        wa[b][1][0] = *(const f16x8*)(p_ + WTERM);                       \
        wa[b][1][1] = *(const f16x8*)(p_ + WTERM + 512);                 \
    } while (0)

#define COMPUTE(b)                                                       \
    do {                                                                 \
        _Pragma("unroll")                                                \
        for (int m = 0; m < 2; ++m) {                                    \
            f16x8 a1, a2;                                                \
            _Pragma("unroll")                                            \
            for (int h = 0; h < 2; ++h) {                                \
                _Pragma("unroll")                                        \
                for (int j = 0; j < 4; ++j) {                            \
                    float f_ = xa[b][m][h][j];                           \
                    _Float16 hi_ = (_Float16)f_;                         \
                    float r_ = (f_ - (float)hi_) * LO_SCALE;             \
                    a1[h * 4 + j] = hi_;                                 \
                    a2[h * 4 + j] = (_Float16)r_;                        \
                }                                                        \
            }                                                            \
            _Pragma("unroll")                                            \
            for (int n = 0; n < 2; ++n) {                                \
                acc[m][n]  = __builtin_amdgcn_mfma_f32_16x16x32_f16(     \
                                 a1, wa[b][0][n], acc[m][n], 0, 0, 0);   \
                accL[m][n] = __builtin_amdgcn_mfma_f32_16x16x32_f16(     \
                                 a1, wa[b][1][n], accL[m][n], 0, 0, 0);  \
                accL[m][n] = __builtin_amdgcn_mfma_f32_16x16x32_f16(     \
                                 a2, wa[b][0][n], accL[m][n], 0, 0, 0);  \
            }                                                            \
        }                                                                \
    } while (0)

    LOADX(0, 0); LOADW(0, 0);
#pragma unroll 1
    for (int ks = 0; ks < KSTEPS - 2; ks += 2) {
        LOADX(ks + 1, 1); LOADW(ks + 1, 1);
        COMPUTE(0);
        LOADX(ks + 2, 0); LOADW(ks + 2, 0);
        COMPUTE(1);
    }
    LOADX(KSTEPS - 1, 1); LOADW(KSTEPS - 1, 1);
    COMPUTE(0);          // step 126
    COMPUTE(1);          // step 127

#undef LOADX
#undef LOADW
#undef COMPUTE

    // epilogue: D row = g*4+q (M side), col = r (N side)
#pragma unroll
    for (int m = 0; m < 2; ++m)
#pragma unroll
        for (int n = 0; n < 2; ++n)
#pragma unroll
            for (int q = 0; q < 4; ++q) {
                float v = acc[m][n][q] + accL[m][n][q] * INV_LO_SCALE;
                logits[(size_t)(row0 + m * 16 + g * 4 + q) * NE + eh * 32 + n * 16 + r] = v;
            }
}

// ---------------- router: softmax + top-8 + L1 renorm -----------------------
__global__ __launch_bounds__(256, 1)
void router_kernel(const float* __restrict__ logits, float* __restrict__ scores,
                   float* __restrict__ wts, float* __restrict__ inds, int N)
{
    const int token = blockIdx.x * 4 + (threadIdx.x >> 6);
    const int lane  = threadIdx.x & 63;
    if (token >= N) return;

    const float l = logits[(size_t)token * NE + lane];

    float m = l;
#pragma unroll
    for (int off = 32; off >= 1; off >>= 1)
        m = fmaxf(m, __shfl_xor(m, off, 64));
    const float p = expf(l - m);
    float s = p;
#pragma unroll
    for (int off = 32; off >= 1; off >>= 1)
        s += __shfl_xor(s, off, 64);
    const float sc = p / s;
    scores[(size_t)token * NE + lane] = sc;

    float cur = sc;
    float tv[TOPK];
    int   ti[TOPK];
    float sum8 = 0.0f;
#pragma unroll
    for (int k = 0; k < TOPK; ++k) {
        float v = cur; int i = lane;
#pragma unroll
        for (int off = 32; off >= 1; off >>= 1) {
            float ov = __shfl_xor(v, off, 64);
            int   oi = __shfl_xor(i, off, 64);
            if (ov > v || (ov == v && oi < i)) { v = ov; i = oi; }
        }
        tv[k] = v; ti[k] = i;
        sum8 += v;
        if (lane == i) cur = -1.0f;
    }

    if (lane == 0) {
#pragma unroll
        for (int k = 0; k < TOPK; ++k) {
            wts[(size_t)token * TOPK + k]  = tv[k] / sum8;
            inds[(size_t)token * TOPK + k] = (float)ti[k];
        }
    }
}

extern "C" void kernel_launch(void* const* d_in, const int* in_sizes, int n_in,
                              void* d_out, int out_size, void* d_ws, size_t ws_size,
                              hipStream_t stream)
{
    const float* x = (const float*)d_in[0];
    const float* W = (const float*)d_in[1];
    const int N = in_sizes[0] / H_DIM;   // 16384

    float* out    = (float*)d_out;
    float* scores = out;                          // [N,64]
    float* logits = out + (size_t)N * NE;         // [N,64]
    float* wts    = out + (size_t)2 * N * NE;     // [N,8]
    float* inds   = wts + (size_t)N * TOPK;       // [N,8] as float

    _Float16* pk = (_Float16*)d_ws;               // needs 2 * 262144 * 2B = 1 MB

    pack_w_kernel<<<(NE * H_DIM) / 256, 256, 0, stream>>>(W, pk);
    moe_logits_mfma<<<N / 32, 128, 0, stream>>>(x, pk, logits);
    router_kernel<<<(N + 3) / 4, 256, 0, stream>>>(logits, scores, wts, inds, N);
}

// Round 5
// 115.009 us; speedup vs baseline: 4.6227x; 1.0234x over previous
//
#include <hip/hip_runtime.h>
#include <math.h>

#define H_DIM  4096
#define NE     64
#define TOPK   8
#define KHALF  2048               // K per split
#define KST    64                 // k-steps of 32 per wave (KHALF/32)
#define WTERM  (NE * H_DIM)       // 262144 elems per packed-W term plane
#define LO_SCALE 2048.0f          // 2^11
#define INV_LO_SCALE (1.0f / 2048.0f)

using f16x8  = __attribute__((ext_vector_type(8))) _Float16;
using hp16x2 = __attribute__((ext_vector_type(2))) __fp16;   // cvt_pkrtz return type
using f32x4  = __attribute__((ext_vector_type(4))) float;

// ---------------- W pre-pack: fp16 2-term split in MFMA B-fragment order ----
// pk[term][kstep][nf][lane][8]: lane = g*16 + (e&15), slot j -> k = kstep*32 + g*8 + j
__global__ __launch_bounds__(256, 1)
void pack_w_kernel(const float* __restrict__ W, _Float16* __restrict__ pk)
{
    int id = blockIdx.x * 256 + threadIdx.x;          // 0 .. 262143
    int e = id >> 12;                                  // / 4096
    int k = id & 4095;
    float f = W[id];
    _Float16 h = (_Float16)f;                          // RNE
    float r = (f - (float)h) * LO_SCALE;               // exact residual, scaled to fp16-normal range
    _Float16 l = (_Float16)r;
    int nf = e >> 4, rr = e & 15;
    int kstep = k >> 5, g = (k >> 3) & 3, j = k & 7;
    int lane = g * 16 + rr;
    size_t idx = (size_t)(kstep * 4 + nf) * 512 + (size_t)lane * 8 + j;
    pk[idx] = h;
    pk[WTERM + idx] = l;
}

// ---------------- main GEMM: partial[kh] = x[:, kh*2048 : +2048] . W^T ------
// wave = 16 tokens x 64 experts; block = 4 waves (64 tokens); grid = 512
// (256 token-groups x 2 K-halves) -> 2048 waves = 2 waves/SIMD
__global__ __launch_bounds__(256, 2)
void moe_logits_mfma(const float* __restrict__ x, const _Float16* __restrict__ pk,
                     float* __restrict__ part0, float* __restrict__ part1)
{
    const int lane = threadIdx.x & 63;
    const int wid  = threadIdx.x >> 6;          // 0..3 token sub-group
    const int kh   = blockIdx.x & 1;            // K half
    const int tg   = blockIdx.x >> 1;           // 0..255 token group of 64
    const int row0 = tg * 64 + wid * 16;
    const int g = lane >> 4, r = lane & 15;

    const float* xp = x + (size_t)(row0 + r) * H_DIM + kh * KHALF + g * 8;
    const _Float16* wp = pk + (size_t)(kh * KST) * 2048 + (size_t)lane * 8;

    f32x4 acc[4], accL[4];
#pragma unroll
    for (int nf = 0; nf < 4; ++nf) { acc[nf] = (f32x4)0.0f; accL[nf] = (f32x4)0.0f; }

    f32x4 xa[3][2];        // [buf][half-of-8]
    f16x8 wa[3][2][4];     // [buf][term][nf]

#define LOADX(ks, b)                                                     \
    do {                                                                 \
        xa[b][0] = *(const f32x4*)(xp + (ks) * 32);                      \
        xa[b][1] = *(const f32x4*)(xp + (ks) * 32 + 4);                  \
    } while (0)

#define LOADW(ks, b)                                                     \
    do {                                                                 \
        const _Float16* p_ = wp + (size_t)(ks) * 2048;                   \
        wa[b][0][0] = *(const f16x8*)(p_);                               \
        wa[b][0][1] = *(const f16x8*)(p_ + 512);                         \
        wa[b][0][2] = *(const f16x8*)(p_ + 1024);                        \
        wa[b][0][3] = *(const f16x8*)(p_ + 1536);                        \
        wa[b][1][0] = *(const f16x8*)(p_ + WTERM);                       \
        wa[b][1][1] = *(const f16x8*)(p_ + WTERM + 512);                 \
        wa[b][1][2] = *(const f16x8*)(p_ + WTERM + 1024);                \
        wa[b][1][3] = *(const f16x8*)(p_ + WTERM + 1536);                \
    } while (0)

#define COMPUTE(b)                                                       \
    do {                                                                 \
        f16x8 a1, a2;                                                    \
        _Pragma("unroll")                                                \
        for (int h = 0; h < 2; ++h) {                                    \
            _Pragma("unroll")                                            \
            for (int j = 0; j < 4; j += 2) {                             \
                float v0 = xa[b][h][j];                                  \
                float v1 = xa[b][h][j + 1];                              \
                hp16x2 hp = __builtin_amdgcn_cvt_pkrtz(v0, v1);          \
                float r0 = (v0 - (float)hp[0]) * LO_SCALE;               \
                float r1 = (v1 - (float)hp[1]) * LO_SCALE;               \
                hp16x2 lp = __builtin_amdgcn_cvt_pkrtz(r0, r1);          \
                a1[h * 4 + j]     = (_Float16)hp[0];                     \
                a1[h * 4 + j + 1] = (_Float16)hp[1];                     \
                a2[h * 4 + j]     = (_Float16)lp[0];                     \
                a2[h * 4 + j + 1] = (_Float16)lp[1];                     \
            }                                                            \
        }                                                                \
        _Pragma("unroll")                                                \
        for (int nf = 0; nf < 4; ++nf) {                                 \
            acc[nf]  = __builtin_amdgcn_mfma_f32_16x16x32_f16(           \
                           a1, wa[b][0][nf], acc[nf], 0, 0, 0);          \
            accL[nf] = __builtin_amdgcn_mfma_f32_16x16x32_f16(           \
                           a1, wa[b][1][nf], accL[nf], 0, 0, 0);         \
            accL[nf] = __builtin_amdgcn_mfma_f32_16x16x32_f16(           \
                           a2, wa[b][0][nf], accL[nf], 0, 0, 0);         \
        }                                                                \
    } while (0)

    // prologue: 2-deep
    LOADX(0, 0); LOADW(0, 0);
    LOADX(1, 1); LOADW(1, 1);

#pragma unroll 1
    for (int ks = 0; ks < KST - 4; ks += 3) {
        LOADX(ks + 2, 2); LOADW(ks + 2, 2); COMPUTE(0);
        LOADX(ks + 3, 0); LOADW(ks + 3, 0); COMPUTE(1);
        LOADX(ks + 4, 1); LOADW(ks + 4, 1); COMPUTE(2);
    }
    // epilogue: steps 60..63 (x0=60, x1=61 live in bufs 0,1)
    LOADX(62, 2); LOADW(62, 2); COMPUTE(0);   // 60
    LOADX(63, 0); LOADW(63, 0); COMPUTE(1);   // 61
    COMPUTE(2);                               // 62
    COMPUTE(0);                               // 63

#undef LOADX
#undef LOADW
#undef COMPUTE

    // store partial tile: D row (token) = g*4+q, col (expert) = nf*16+r
    float* outp = kh == 0 ? part0 : part1;
#pragma unroll
    for (int nf = 0; nf < 4; ++nf)
#pragma unroll
        for (int q = 0; q < 4; ++q) {
            float v = acc[nf][q] + accL[nf][q] * INV_LO_SCALE;
            outp[(size_t)(row0 + g * 4 + q) * NE + nf * 16 + r] = v;
        }
}

// ---------------- router: sum partials, softmax + top-8 + L1 renorm ---------
// NOTE: scores aliases p0 and logits aliases p1 — each wave reads only its own
// token row before writing it; rows are wave-exclusive, so this is race-free.
__global__ __launch_bounds__(256, 1)
void router_kernel(const float* p0, const float* p1, float* scores,
                   float* logits, float* wts, float* inds, int N)
{
    const int token = blockIdx.x * 4 + (threadIdx.x >> 6);
    const int lane  = threadIdx.x & 63;
    if (token >= N) return;

    const float l = p0[(size_t)token * NE + lane] + p1[(size_t)token * NE + lane];

    float m = l;
#pragma unroll
    for (int off = 32; off >= 1; off >>= 1)
        m = fmaxf(m, __shfl_xor(m, off, 64));
    const float p = expf(l - m);
    float s = p;
#pragma unroll
    for (int off = 32; off >= 1; off >>= 1)
        s += __shfl_xor(s, off, 64);
    const float sc = p / s;

    scores[(size_t)token * NE + lane] = sc;
    logits[(size_t)token * NE + lane] = l;

    float cur = sc;
    float tv[TOPK];
    int   ti[TOPK];
    float sum8 = 0.0f;
#pragma unroll
    for (int k = 0; k < TOPK; ++k) {
        float v = cur; int i = lane;
#pragma unroll
        for (int off = 32; off >= 1; off >>= 1) {
            float ov = __shfl_xor(v, off, 64);
            int   oi = __shfl_xor(i, off, 64);
            if (ov > v || (ov == v && oi < i)) { v = ov; i = oi; }
        }
        tv[k] = v; ti[k] = i;
        sum8 += v;
        if (lane == i) cur = -1.0f;   // scores > 0, so -1 masks
    }

    if (lane == 0) {
#pragma unroll
        for (int k = 0; k < TOPK; ++k) {
            wts[(size_t)token * TOPK + k]  = tv[k] / sum8;
            inds[(size_t)token * TOPK + k] = (float)ti[k];
        }
    }
}

extern "C" void kernel_launch(void* const* d_in, const int* in_sizes, int n_in,
                              void* d_out, int out_size, void* d_ws, size_t ws_size,
                              hipStream_t stream)
{
    const float* x = (const float*)d_in[0];
    const float* W = (const float*)d_in[1];
    const int N = in_sizes[0] / H_DIM;   // 16384

    float* out    = (float*)d_out;
    float* scores = out;                          // [N,64]  (doubles as partial kh=0)
    float* logits = out + (size_t)N * NE;         // [N,64]  (doubles as partial kh=1)
    float* wts    = out + (size_t)2 * N * NE;     // [N,8]
    float* inds   = wts + (size_t)N * TOPK;       // [N,8] as float

    _Float16* pk = (_Float16*)d_ws;               // 2 * 262144 * 2B = 1 MB

    pack_w_kernel<<<(NE * H_DIM) / 256, 256, 0, stream>>>(W, pk);
    moe_logits_mfma<<<(N / 64) * 2, 256, 0, stream>>>(x, pk, scores, logits);
    router_kernel<<<(N + 3) / 4, 256, 0, stream>>>(scores, logits, scores, logits,
                                                   wts, inds, N);
}

// Round 6
// 100.740 us; speedup vs baseline: 5.2774x; 1.1416x over previous
//
#include <hip/hip_runtime.h>
#include <math.h>

#define H_DIM  4096
#define NE     64
#define TOPK   8
#define KHALF  2048               // K per split
#define KST    64                 // k-steps of 32 per wave (KHALF/32)
#define WTERM  (NE * H_DIM)       // 262144 elems per packed-W term plane
#define LO_SCALE 2048.0f          // 2^11
#define INV_LO_SCALE (1.0f / 2048.0f)

using f16x8  = __attribute__((ext_vector_type(8))) _Float16;
using hp16x2 = __attribute__((ext_vector_type(2))) __fp16;   // cvt_pkrtz return type
using f32x4  = __attribute__((ext_vector_type(4))) float;

// ---------------- W pre-pack: fp16 2-term split in MFMA B-fragment order ----
// pk[term][kstep][nf][lane][8]: lane = g*16 + (e&15), slot j -> k = kstep*32 + g*8 + j
// per-kstep slice (2048 f16 = 4 KB) is contiguous -> LDS-stageable.
__global__ __launch_bounds__(256, 1)
void pack_w_kernel(const float* __restrict__ W, _Float16* __restrict__ pk)
{
    int id = blockIdx.x * 256 + threadIdx.x;          // 0 .. 262143
    int e = id >> 12;                                  // / 4096
    int k = id & 4095;
    float f = W[id];
    _Float16 h = (_Float16)f;                          // RNE
    float r = (f - (float)h) * LO_SCALE;               // exact residual, scaled to fp16-normal range
    _Float16 l = (_Float16)r;
    int nf = e >> 4, rr = e & 15;
    int kstep = k >> 5, g = (k >> 3) & 3, j = k & 7;
    int lane = g * 16 + rr;
    size_t idx = (size_t)(kstep * 4 + nf) * 512 + (size_t)lane * 8 + j;
    pk[idx] = h;
    pk[WTERM + idx] = l;
}

// ---------------- main GEMM: partial[kh] = x[:, kh*2048 : +2048] . W^T ------
// block = 4 waves x 16 tokens (64 tokens), one K half; W k-slice shared via LDS.
// grid = 512 (256 token-groups x 2 K-halves) -> 2 blocks/CU, 8 waves/CU.
__global__ __launch_bounds__(256, 2)
void moe_logits_mfma(const float* __restrict__ x, const _Float16* __restrict__ pk,
                     float* __restrict__ part0, float* __restrict__ part1)
{
    const int lane = threadIdx.x & 63;
    const int wid  = threadIdx.x >> 6;          // 0..3 token sub-group / stage quarter
    const int kh   = blockIdx.x & 1;            // K half
    const int tg   = blockIdx.x >> 1;           // 0..255 token group of 64
    const int row0 = tg * 64 + wid * 16;
    const int g = lane >> 4, r = lane & 15;

    const float* xp = x + (size_t)(row0 + r) * H_DIM + kh * KHALF + g * 8;
    // staging source: this wave's quarter of the per-kstep hi slice
    const _Float16* wsrc = pk + (size_t)(kh * KST) * 2048 + wid * 512 + (size_t)lane * 8;

    // [buf][ term*2048 + nf*512 + lane*8 ] : 2 x 8 KB
    __shared__ _Float16 sw[2][4096];
    const int lbase = wid * 512 + lane * 8;

    f32x4 acc[4], accL[4];
#pragma unroll
    for (int nf = 0; nf < 4; ++nf) { acc[nf] = (f32x4)0.0f; accL[nf] = (f32x4)0.0f; }

    f32x4 xa[2][2];        // [buf][half-of-8]
    f16x8 wst0, wst1;      // staged W granules (hi, lo) in flight

    // prologue: load x(0), stage W(0) into buf 0
    xa[0][0] = *(const f32x4*)(xp);
    xa[0][1] = *(const f32x4*)(xp + 4);
    wst0 = *(const f16x8*)(wsrc);
    wst1 = *(const f16x8*)(wsrc + WTERM);
    *(f16x8*)&sw[0][lbase]        = wst0;
    *(f16x8*)&sw[0][2048 + lbase] = wst1;
    __syncthreads();

#define STEP(ks, buf, PF)                                                \
    do {                                                                 \
        if (PF) {                                                        \
            xa[buf ^ 1][0] = *(const f32x4*)(xp + ((ks) + 1) * 32);      \
            xa[buf ^ 1][1] = *(const f32x4*)(xp + ((ks) + 1) * 32 + 4);  \
            wst0 = *(const f16x8*)(wsrc + ((ks) + 1) * 2048);            \
            wst1 = *(const f16x8*)(wsrc + ((ks) + 1) * 2048 + WTERM);    \
        }                                                                \
        f16x8 wa[2][4];                                                  \
        _Pragma("unroll")                                                \
        for (int t = 0; t < 2; ++t)                                      \
            _Pragma("unroll")                                            \
            for (int nf = 0; nf < 4; ++nf)                               \
                wa[t][nf] = *(const f16x8*)&sw[buf][t * 2048 + nf * 512 + lane * 8]; \
        f16x8 a1, a2;                                                    \
        _Pragma("unroll")                                                \
        for (int h = 0; h < 2; ++h) {                                    \
            _Pragma("unroll")                                            \
            for (int j = 0; j < 4; j += 2) {                             \
                float v0 = xa[buf][h][j];                                \
                float v1 = xa[buf][h][j + 1];                            \
                hp16x2 hp = __builtin_amdgcn_cvt_pkrtz(v0, v1);          \
                float r0 = (v0 - (float)hp[0]) * LO_SCALE;               \
                float r1 = (v1 - (float)hp[1]) * LO_SCALE;               \
                hp16x2 lp = __builtin_amdgcn_cvt_pkrtz(r0, r1);          \
                a1[h * 4 + j]     = (_Float16)hp[0];                     \
                a1[h * 4 + j + 1] = (_Float16)hp[1];                     \
                a2[h * 4 + j]     = (_Float16)lp[0];                     \
                a2[h * 4 + j + 1] = (_Float16)lp[1];                     \
            }                                                            \
        }                                                                \
        _Pragma("unroll")                                                \
        for (int nf = 0; nf < 4; ++nf) {                                 \
            acc[nf]  = __builtin_amdgcn_mfma_f32_16x16x32_f16(           \
                           a1, wa[0][nf], acc[nf], 0, 0, 0);             \
            accL[nf] = __builtin_amdgcn_mfma_f32_16x16x32_f16(           \
                           a1, wa[1][nf], accL[nf], 0, 0, 0);            \
            accL[nf] = __builtin_amdgcn_mfma_f32_16x16x32_f16(           \
                           a2, wa[0][nf], accL[nf], 0, 0, 0);            \
        }                                                                \
        if (PF) {                                                        \
            *(f16x8*)&sw[buf ^ 1][lbase]        = wst0;                  \
            *(f16x8*)&sw[buf ^ 1][2048 + lbase] = wst1;                  \
        }                                                                \
        __syncthreads();                                                 \
    } while (0)

#pragma unroll 1
    for (int ks2 = 0; ks2 < KST / 2 - 1; ++ks2) {
        STEP(2 * ks2,     0, 1);
        STEP(2 * ks2 + 1, 1, 1);
    }
    STEP(KST - 2, 0, 1);
    STEP(KST - 1, 1, 0);

#undef STEP

    // store partial tile: D row (token) = g*4+q, col (expert) = nf*16+r
    float* outp = kh == 0 ? part0 : part1;
#pragma unroll
    for (int nf = 0; nf < 4; ++nf)
#pragma unroll
        for (int q = 0; q < 4; ++q) {
            float v = acc[nf][q] + accL[nf][q] * INV_LO_SCALE;
            outp[(size_t)(row0 + g * 4 + q) * NE + nf * 16 + r] = v;
        }
}

// ---------------- router: sum partials, softmax + top-8 + L1 renorm ---------
// NOTE: scores aliases p0 and logits aliases p1 — each wave reads only its own
// token row before writing it; rows are wave-exclusive, so this is race-free.
__global__ __launch_bounds__(256, 1)
void router_kernel(const float* p0, const float* p1, float* scores,
                   float* logits, float* wts, float* inds, int N)
{
    const int token = blockIdx.x * 4 + (threadIdx.x >> 6);
    const int lane  = threadIdx.x & 63;
    if (token >= N) return;

    const float l = p0[(size_t)token * NE + lane] + p1[(size_t)token * NE + lane];

    float m = l;
#pragma unroll
    for (int off = 32; off >= 1; off >>= 1)
        m = fmaxf(m, __shfl_xor(m, off, 64));
    const float p = expf(l - m);
    float s = p;
#pragma unroll
    for (int off = 32; off >= 1; off >>= 1)
        s += __shfl_xor(s, off, 64);
    const float sc = p / s;

    scores[(size_t)token * NE + lane] = sc;
    logits[(size_t)token * NE + lane] = l;

    float cur = sc;
    float tv[TOPK];
    int   ti[TOPK];
    float sum8 = 0.0f;
#pragma unroll
    for (int k = 0; k < TOPK; ++k) {
        float v = cur; int i = lane;
#pragma unroll
        for (int off = 32; off >= 1; off >>= 1) {
            float ov = __shfl_xor(v, off, 64);
            int   oi = __shfl_xor(i, off, 64);
            if (ov > v || (ov == v && oi < i)) { v = ov; i = oi; }
        }
        tv[k] = v; ti[k] = i;
        sum8 += v;
        if (lane == i) cur = -1.0f;   // scores > 0, so -1 masks
    }

    if (lane == 0) {
#pragma unroll
        for (int k = 0; k < TOPK; ++k) {
            wts[(size_t)token * TOPK + k]  = tv[k] / sum8;
            inds[(size_t)token * TOPK + k] = (float)ti[k];
        }
    }
}

extern "C" void kernel_launch(void* const* d_in, const int* in_sizes, int n_in,
                              void* d_out, int out_size, void* d_ws, size_t ws_size,
                              hipStream_t stream)
{
    const float* x = (const float*)d_in[0];
    const float* W = (const float*)d_in[1];
    const int N = in_sizes[0] / H_DIM;   // 16384

    float* out    = (float*)d_out;
    float* scores = out;                          // [N,64]  (doubles as partial kh=0)
    float* logits = out + (size_t)N * NE;         // [N,64]  (doubles as partial kh=1)
    float* wts    = out + (size_t)2 * N * NE;     // [N,8]
    float* inds   = wts + (size_t)N * TOPK;       // [N,8] as float

    _Float16* pk = (_Float16*)d_ws;               // 2 * 262144 * 2B = 1 MB

    pack_w_kernel<<<(NE * H_DIM) / 256, 256, 0, stream>>>(W, pk);
    moe_logits_mfma<<<(N / 64) * 2, 256, 0, stream>>>(x, pk, scores, logits);
    router_kernel<<<(N + 3) / 4, 256, 0, stream>>>(scores, logits, scores, logits,
                                                   wts, inds, N);
}

// Round 7
// 83.436 us; speedup vs baseline: 6.3719x; 1.2074x over previous
//
#include <hip/hip_runtime.h>
#include <math.h>

#define H_DIM  4096
#define NE     64
#define TOPK   8
#define KHALF  2048               // K per split
#define KST    64                 // k-steps of 32 per wave (KHALF/32)
#define WTERM  (NE * H_DIM)       // 262144 elems per packed-W term plane
#define LO_SCALE 2048.0f          // 2^11
#define INV_LO_SCALE (1.0f / 2048.0f)

using f16x8  = __attribute__((ext_vector_type(8))) _Float16;
using hp16x2 = __attribute__((ext_vector_type(2))) __fp16;   // cvt_pkrtz return type
using f32x4  = __attribute__((ext_vector_type(4))) float;

// ---------------- W pre-pack: fp16 2-term split in MFMA B-fragment order ----
// pk[term][kstep][nf][lane][8]: lane = g*16 + (e&15), slot j -> k = kstep*32 + g*8 + j
__global__ __launch_bounds__(256, 1)
void pack_w_kernel(const float* __restrict__ W, _Float16* __restrict__ pk)
{
    int id = blockIdx.x * 256 + threadIdx.x;          // 0 .. 262143
    int e = id >> 12;                                  // / 4096
    int k = id & 4095;
    float f = W[id];
    _Float16 h = (_Float16)f;                          // RNE
    float r = (f - (float)h) * LO_SCALE;               // exact residual, scaled to fp16-normal range
    _Float16 l = (_Float16)r;
    int nf = e >> 4, rr = e & 15;
    int kstep = k >> 5, g = (k >> 3) & 3, j = k & 7;
    int lane = g * 16 + rr;
    size_t idx = (size_t)(kstep * 4 + nf) * 512 + (size_t)lane * 8 + j;
    pk[idx] = h;
    pk[WTERM + idx] = l;
}

// ---------------- main GEMM: partial[kh] = x[:, kh*2048 : +2048] . W^T ------
// block = 4 waves x 16 tokens (64 tokens), one K half; W k-slice shared via LDS.
// 32 phases x 2 ksteps; raw s_barrier + lgkmcnt(0) only -> global loads stay
// in flight across barriers (no vmcnt(0) drain).
__global__ __launch_bounds__(256, 2)
void moe_logits_mfma(const float* __restrict__ x, const _Float16* __restrict__ pk,
                     float* __restrict__ part0, float* __restrict__ part1)
{
    const int lane = threadIdx.x & 63;
    const int wid  = threadIdx.x >> 6;          // 0..3 token sub-group / stage quarter
    const int kh   = blockIdx.x & 1;            // K half
    const int tg   = blockIdx.x >> 1;           // 0..255 token group of 64
    const int row0 = tg * 64 + wid * 16;
    const int g = lane >> 4, r = lane & 15;

    const float* xq = x + (size_t)(row0 + r) * H_DIM + kh * KHALF + g * 8;
    // staging source: this wave's quarter of each per-kstep slice
    const _Float16* wq = pk + (size_t)(kh * KST) * 2048 + wid * 512 + (size_t)lane * 8;

    // [buf][kstep-in-phase][ term*2048 + nf*512 + lane*8 ] : 2 x 16 KB
    __shared__ _Float16 sw[2][2][4096];
    const int lbase = wid * 512 + lane * 8;

    f32x4 acc[4], accL[4];
#pragma unroll
    for (int nf = 0; nf < 4; ++nf) { acc[nf] = (f32x4)0.0f; accL[nf] = (f32x4)0.0f; }

    f32x4 xr[2][2][2];     // [phase-buf][kip][half]  (x for phase P in xr[P&1])
    f16x8 wr[2][2][2];     // [phase-buf][kip][term]  (W[P+1] lives in wr[(P+1)&1])

    // ---- prologue: x[ph0], x[ph1], W[ph0]->wr[0], W[ph1]->wr[1]; stage W[ph0]
    xr[0][0][0] = *(const f32x4*)(xq);        xr[0][0][1] = *(const f32x4*)(xq + 4);
    xr[0][1][0] = *(const f32x4*)(xq + 32);   xr[0][1][1] = *(const f32x4*)(xq + 36);
    xr[1][0][0] = *(const f32x4*)(xq + 64);   xr[1][0][1] = *(const f32x4*)(xq + 68);
    xr[1][1][0] = *(const f32x4*)(xq + 96);   xr[1][1][1] = *(const f32x4*)(xq + 100);
#pragma unroll
    for (int kip = 0; kip < 2; ++kip)
#pragma unroll
        for (int t = 0; t < 2; ++t) {
            wr[0][kip][t] = *(const f16x8*)(wq + kip * 2048 + t * WTERM);
            wr[1][kip][t] = *(const f16x8*)(wq + 4096 + kip * 2048 + t * WTERM);
        }
#pragma unroll
    for (int kip = 0; kip < 2; ++kip)
#pragma unroll
        for (int t = 0; t < 2; ++t)
            *(f16x8*)&sw[0][kip][t * 2048 + lbase] = wr[0][kip][t];
    asm volatile("s_waitcnt lgkmcnt(0)\n\ts_barrier" ::: "memory");

    // PHASE(b_, XOFF_, DSW_, PFW_, PFX_):
    //  b_: phase parity (LDS/reg buffer), XOFF_: x col offset within pair (0/64)
    //  DSW_: ds_write W[P+1] -> sw[b^1];  PFW_: issue W[P+2] -> wr[b];
    //  PFX_: issue x[P+2] -> xr[b] (after last conv use of xr[b])
#define PHASE(b_, XOFF_, DSW_, PFW_, PFX_)                                     \
    do {                                                                       \
        if (DSW_) {                                                            \
            _Pragma("unroll")                                                  \
            for (int kip = 0; kip < 2; ++kip)                                  \
                _Pragma("unroll")                                              \
                for (int t = 0; t < 2; ++t)                                    \
                    *(f16x8*)&sw[(b_) ^ 1][kip][t * 2048 + lbase] =            \
                        wr[(b_) ^ 1][kip][t];                                  \
        }                                                                      \
        if (PFW_) {                                                            \
            _Pragma("unroll")                                                  \
            for (int kip = 0; kip < 2; ++kip)                                  \
                _Pragma("unroll")                                              \
                for (int t = 0; t < 2; ++t)                                    \
                    wr[b_][kip][t] = *(const f16x8*)(wq + (b_) * 4096 + 8192   \
                                                     + kip * 2048 + t * WTERM);\
        }                                                                      \
        _Pragma("unroll")                                                      \
        for (int kip = 0; kip < 2; ++kip) {                                    \
            f16x8 wa[2][4];                                                    \
            _Pragma("unroll")                                                  \
            for (int t = 0; t < 2; ++t)                                        \
                _Pragma("unroll")                                              \
                for (int nf = 0; nf < 4; ++nf)                                 \
                    wa[t][nf] = *(const f16x8*)                                \
                        &sw[b_][kip][t * 2048 + nf * 512 + lane * 8];          \
            f16x8 a1, a2;                                                      \
            _Pragma("unroll")                                                  \
            for (int h = 0; h < 2; ++h)                                        \
                _Pragma("unroll")                                              \
                for (int j = 0; j < 4; j += 2) {                               \
                    float v0 = xr[b_][kip][h][j];                              \
                    float v1 = xr[b_][kip][h][j + 1];                          \
                    hp16x2 hp = __builtin_amdgcn_cvt_pkrtz(v0, v1);            \
                    float r0 = (v0 - (float)hp[0]) * LO_SCALE;                 \
                    float r1 = (v1 - (float)hp[1]) * LO_SCALE;                 \
                    hp16x2 lp = __builtin_amdgcn_cvt_pkrtz(r0, r1);            \
                    a1[h * 4 + j]     = (_Float16)hp[0];                       \
                    a1[h * 4 + j + 1] = (_Float16)hp[1];                       \
                    a2[h * 4 + j]     = (_Float16)lp[0];                       \
                    a2[h * 4 + j + 1] = (_Float16)lp[1];                       \
                }                                                              \
            if ((kip == 1) && (PFX_)) {                                        \
                xr[b_][0][0] = *(const f32x4*)(xq + (XOFF_) + 128);            \
                xr[b_][0][1] = *(const f32x4*)(xq + (XOFF_) + 132);            \
                xr[b_][1][0] = *(const f32x4*)(xq + (XOFF_) + 160);            \
                xr[b_][1][1] = *(const f32x4*)(xq + (XOFF_) + 164);            \
            }                                                                  \
            _Pragma("unroll")                                                  \
            for (int nf = 0; nf < 4; ++nf) {                                   \
                acc[nf]  = __builtin_amdgcn_mfma_f32_16x16x32_f16(             \
                               a1, wa[0][nf], acc[nf], 0, 0, 0);               \
                accL[nf] = __builtin_amdgcn_mfma_f32_16x16x32_f16(             \
                               a1, wa[1][nf], accL[nf], 0, 0, 0);              \
                accL[nf] = __builtin_amdgcn_mfma_f32_16x16x32_f16(             \
                               a2, wa[0][nf], accL[nf], 0, 0, 0);              \
            }                                                                  \
        }                                                                      \
        asm volatile("s_waitcnt lgkmcnt(0)\n\ts_barrier" ::: "memory");        \
    } while (0)

    // phases 0..29 (15 pairs), full pipeline
#pragma unroll 1
    for (int it = 0; it < 15; ++it) {
        PHASE(0, 0,  1, 1, 1);
        PHASE(1, 64, 1, 1, 1);
        xq += 128;
        wq += 8192;
    }
    // phase 30: stage W[31], no more prefetches
    PHASE(0, 0,  1, 0, 0);
    // phase 31: compute only
    PHASE(1, 64, 0, 0, 0);

#undef PHASE

    // store partial tile: D row (token) = g*4+q, col (expert) = nf*16+r
    float* outp = kh == 0 ? part0 : part1;
#pragma unroll
    for (int nf = 0; nf < 4; ++nf)
#pragma unroll
        for (int q = 0; q < 4; ++q) {
            float v = acc[nf][q] + accL[nf][q] * INV_LO_SCALE;
            outp[(size_t)(row0 + g * 4 + q) * NE + nf * 16 + r] = v;
        }
}

// ---------------- router: sum partials, softmax + top-8 + L1 renorm ---------
// NOTE: scores aliases p0 and logits aliases p1 — each wave reads only its own
// token row before writing it; rows are wave-exclusive, so this is race-free.
__global__ __launch_bounds__(256, 1)
void router_kernel(const float* p0, const float* p1, float* scores,
                   float* logits, float* wts, float* inds, int N)
{
    const int token = blockIdx.x * 4 + (threadIdx.x >> 6);
    const int lane  = threadIdx.x & 63;
    if (token >= N) return;

    const float l = p0[(size_t)token * NE + lane] + p1[(size_t)token * NE + lane];

    float m = l;
#pragma unroll
    for (int off = 32; off >= 1; off >>= 1)
        m = fmaxf(m, __shfl_xor(m, off, 64));
    const float p = expf(l - m);
    float s = p;
#pragma unroll
    for (int off = 32; off >= 1; off >>= 1)
        s += __shfl_xor(s, off, 64);
    const float sc = p / s;

    scores[(size_t)token * NE + lane] = sc;
    logits[(size_t)token * NE + lane] = l;

    float cur = sc;
    float tv[TOPK];
    int   ti[TOPK];
    float sum8 = 0.0f;
#pragma unroll
    for (int k = 0; k < TOPK; ++k) {
        float v = cur; int i = lane;
#pragma unroll
        for (int off = 32; off >= 1; off >>= 1) {
            float ov = __shfl_xor(v, off, 64);
            int   oi = __shfl_xor(i, off, 64);
            if (ov > v || (ov == v && oi < i)) { v = ov; i = oi; }
        }
        tv[k] = v; ti[k] = i;
        sum8 += v;
        if (lane == i) cur = -1.0f;   // scores > 0, so -1 masks
    }

    if (lane == 0) {
#pragma unroll
        for (int k = 0; k < TOPK; ++k) {
            wts[(size_t)token * TOPK + k]  = tv[k] / sum8;
            inds[(size_t)token * TOPK + k] = (float)ti[k];
        }
    }
}

extern "C" void kernel_launch(void* const* d_in, const int* in_sizes, int n_in,
                              void* d_out, int out_size, void* d_ws, size_t ws_size,
                              hipStream_t stream)
{
    const float* x = (const float*)d_in[0];
    const float* W = (const float*)d_in[1];
    const int N = in_sizes[0] / H_DIM;   // 16384

    float* out    = (float*)d_out;
    float* scores = out;                          // [N,64]  (doubles as partial kh=0)
    float* logits = out + (size_t)N * NE;         // [N,64]  (doubles as partial kh=1)
    float* wts    = out + (size_t)2 * N * NE;     // [N,8]
    float* inds   = wts + (size_t)N * TOPK;       // [N,8] as float

    _Float16* pk = (_Float16*)d_ws;               // 2 * 262144 * 2B = 1 MB

    pack_w_kernel<<<(NE * H_DIM) / 256, 256, 0, stream>>>(W, pk);
    moe_logits_mfma<<<(N / 64) * 2, 256, 0, stream>>>(x, pk, scores, logits);
    router_kernel<<<(N + 3) / 4, 256, 0, stream>>>(scores, logits, scores, logits,
                                                   wts, inds, N);
}

// Round 8
// 80.342 us; speedup vs baseline: 6.6173x; 1.0385x over previous
//
#include <hip/hip_runtime.h>
#include <math.h>

#define H_DIM  4096
#define NE     64
#define TOPK   8
#define KHALF  2048               // K per split
#define WTERM  (NE * H_DIM)       // 262144 elems per packed-W term plane
#define LO_SCALE 2048.0f          // 2^11
#define INV_LO_SCALE (1.0f / 2048.0f)

using f16x8  = __attribute__((ext_vector_type(8))) _Float16;
using hp16x2 = __attribute__((ext_vector_type(2))) __fp16;   // cvt_pkrtz return type
using f32x4  = __attribute__((ext_vector_type(4))) float;

// ---------------- W pre-pack: fp16 2-term split in MFMA B-fragment order ----
// pk[term][kstep][nf][lane][8]: lane = g*16 + (e&15), slot j -> k = kstep*32 + g*8 + j
__global__ __launch_bounds__(256, 1)
void pack_w_kernel(const float* __restrict__ W, _Float16* __restrict__ pk)
{
    int id = blockIdx.x * 256 + threadIdx.x;          // 0 .. 262143
    int e = id >> 12;                                  // / 4096
    int k = id & 4095;
    float f = W[id];
    _Float16 h = (_Float16)f;                          // RNE
    float r = (f - (float)h) * LO_SCALE;               // exact residual, scaled to fp16-normal range
    _Float16 l = (_Float16)r;
    int nf = e >> 4, rr = e & 15;
    int kstep = k >> 5, g = (k >> 3) & 3, j = k & 7;
    int lane = g * 16 + rr;
    size_t idx = (size_t)(kstep * 4 + nf) * 512 + (size_t)lane * 8 + j;
    pk[idx] = h;
    pk[WTERM + idx] = l;
}

// ---------------- main GEMM: partial[kh] = x[:, kh*2048 : +2048] . W^T ------
// block = 4 waves x 16 tokens (64 tokens), one K half; W k-slice shared via LDS;
// x staged coalesced -> transposed pad-17 LDS (per-wave private).
// 32 phases x 2 ksteps; raw s_barrier + lgkmcnt(0); counted vmcnt only.
__global__ __launch_bounds__(256, 2)
void moe_logits_mfma(const float* __restrict__ x, const _Float16* __restrict__ pk,
                     float* __restrict__ part0, float* __restrict__ part1)
{
    const int lane = threadIdx.x & 63;
    const int wid  = threadIdx.x >> 6;          // 0..3 token sub-group / stage quarter
    const int kh   = blockIdx.x & 1;            // K half
    const int tg   = blockIdx.x >> 1;           // 0..255 token group of 64
    const int row0 = tg * 64 + wid * 16;
    const int g = lane >> 4, r = lane & 15;

    // coalesced x staging base: instr i covers rows i*4+(lane>>4), 16B at col (lane&15)*4
    const float* xg = x + (size_t)(row0 + (lane >> 4)) * H_DIM + kh * KHALF + (lane & 15) * 4;
    // W staging source: this wave's quarter of each per-kstep slice
    const _Float16* wq = pk + (size_t)(kh * 64) * 2048 + wid * 512 + (size_t)lane * 8;

    __shared__ _Float16 sw[2][2][4096];   // [buf][kip][t*2048+nf*512+lane*8] : 32 KB
    __shared__ float    sx[2][4][1088];   // [buf][wave][col*17 + row]        : 34.8 KB
    const int lbase = wid * 512 + lane * 8;
    const int c0 = (lane & 15) * 4;       // staged col group
    const int rq = lane >> 4;             // staged row-in-quad

    f32x4 acc[4], accL[4];
#pragma unroll
    for (int nf = 0; nf < 4; ++nf) { acc[nf] = (f32x4)0.0f; accL[nf] = (f32x4)0.0f; }

    f32x4 xst[2][4];       // [phase-buf][row-quad]   x for phase P+1 in xst[(P+1)&1]
    f16x8 wr[2][2][2];     // [phase-buf][kip][term]  W for phase P+1 in wr[(P+1)&1]

    // ---- prologue: regs <- x/W of phases 0,1; LDS buf0 <- phase 0
#pragma unroll
    for (int i = 0; i < 4; ++i) {
        xst[0][i] = *(const f32x4*)(xg + i * 4 * H_DIM);
        xst[1][i] = *(const f32x4*)(xg + i * 4 * H_DIM + 64);
    }
#pragma unroll
    for (int kip = 0; kip < 2; ++kip)
#pragma unroll
        for (int t = 0; t < 2; ++t) {
            wr[0][kip][t] = *(const f16x8*)(wq + kip * 2048 + t * WTERM);
            wr[1][kip][t] = *(const f16x8*)(wq + 4096 + kip * 2048 + t * WTERM);
        }
#pragma unroll
    for (int kip = 0; kip < 2; ++kip)
#pragma unroll
        for (int t = 0; t < 2; ++t)
            *(f16x8*)&sw[0][kip][t * 2048 + lbase] = wr[0][kip][t];
#pragma unroll
    for (int i = 0; i < 4; ++i)
#pragma unroll
        for (int j = 0; j < 4; ++j)
            sx[0][wid][(c0 + j) * 17 + i * 4 + rq] = xst[0][i][j];
    asm volatile("s_waitcnt lgkmcnt(0)\n\ts_barrier" ::: "memory");

    // PHASE(b_, DSW_, PFW_, PFX_): compute phase with parity b_;
    //  DSW_: ds_write regs[b^1] (phase P+1) into LDS buf b^1
    //  PFW_/PFX_: issue global loads of phase P+2 into regs[b_]
#define PHASE(b_, DSW_, PFW_, PFX_)                                            \
    do {                                                                       \
        if (DSW_) {                                                            \
            _Pragma("unroll")                                                  \
            for (int kip = 0; kip < 2; ++kip)                                  \
                _Pragma("unroll")                                              \
                for (int t = 0; t < 2; ++t)                                    \
                    *(f16x8*)&sw[(b_) ^ 1][kip][t * 2048 + lbase] =            \
                        wr[(b_) ^ 1][kip][t];                                  \
            _Pragma("unroll")                                                  \
            for (int i = 0; i < 4; ++i)                                        \
                _Pragma("unroll")                                              \
                for (int j = 0; j < 4; ++j)                                    \
                    sx[(b_) ^ 1][wid][(c0 + j) * 17 + i * 4 + rq] =            \
                        xst[(b_) ^ 1][i][j];                                   \
        }                                                                      \
        if (PFW_) {                                                            \
            _Pragma("unroll")                                                  \
            for (int kip = 0; kip < 2; ++kip)                                  \
                _Pragma("unroll")                                              \
                for (int t = 0; t < 2; ++t)                                    \
                    wr[b_][kip][t] = *(const f16x8*)(wq + (b_) * 4096 + 8192   \
                                                     + kip * 2048 + t * WTERM);\
        }                                                                      \
        if (PFX_) {                                                            \
            _Pragma("unroll")                                                  \
            for (int i = 0; i < 4; ++i)                                        \
                xst[b_][i] = *(const f32x4*)(xg + i * 4 * H_DIM                \
                                             + (b_) * 64 + 128);               \
        }                                                                      \
        _Pragma("unroll")                                                      \
        for (int kip = 0; kip < 2; ++kip) {                                    \
            f16x8 wa[2][4];                                                    \
            _Pragma("unroll")                                                  \
            for (int t = 0; t < 2; ++t)                                        \
                _Pragma("unroll")                                              \
                for (int nf = 0; nf < 4; ++nf)                                 \
                    wa[t][nf] = *(const f16x8*)                                \
                        &sw[b_][kip][t * 2048 + nf * 512 + lane * 8];          \
            float xv[8];                                                       \
            _Pragma("unroll")                                                  \
            for (int j = 0; j < 8; ++j)                                        \
                xv[j] = sx[b_][wid][(kip * 32 + g * 8 + j) * 17 + r];          \
            f16x8 a1, a2;                                                      \
            _Pragma("unroll")                                                  \
            for (int j = 0; j < 8; j += 2) {                                   \
                float v0 = xv[j], v1 = xv[j + 1];                              \
                hp16x2 hp = __builtin_amdgcn_cvt_pkrtz(v0, v1);                \
                float r0 = (v0 - (float)hp[0]) * LO_SCALE;                     \
                float r1 = (v1 - (float)hp[1]) * LO_SCALE;                     \
                hp16x2 lp = __builtin_amdgcn_cvt_pkrtz(r0, r1);                \
                a1[j]     = (_Float16)hp[0];                                   \
                a1[j + 1] = (_Float16)hp[1];                                   \
                a2[j]     = (_Float16)lp[0];                                   \
                a2[j + 1] = (_Float16)lp[1];                                   \
            }                                                                  \
            _Pragma("unroll")                                                  \
            for (int nf = 0; nf < 4; ++nf) {                                   \
                acc[nf]  = __builtin_amdgcn_mfma_f32_16x16x32_f16(             \
                               a1, wa[0][nf], acc[nf], 0, 0, 0);               \
                accL[nf] = __builtin_amdgcn_mfma_f32_16x16x32_f16(             \
                               a1, wa[1][nf], accL[nf], 0, 0, 0);              \
                accL[nf] = __builtin_amdgcn_mfma_f32_16x16x32_f16(             \
                               a2, wa[0][nf], accL[nf], 0, 0, 0);              \
            }                                                                  \
        }                                                                      \
        asm volatile("s_waitcnt lgkmcnt(0)\n\ts_barrier" ::: "memory");        \
    } while (0)

    // phases 0..29 (15 pairs), full pipeline
#pragma unroll 1
    for (int it = 0; it < 15; ++it) {
        PHASE(0, 1, 1, 1);
        PHASE(1, 1, 1, 1);
        xg += 128;
        wq += 8192;
    }
    // phase 30: stage phase-31 regs, no more prefetch
    PHASE(0, 1, 0, 0);
    // phase 31: compute only
    PHASE(1, 0, 0, 0);

#undef PHASE

    // store partial tile: D row (token) = g*4+q, col (expert) = nf*16+r
    float* outp = kh == 0 ? part0 : part1;
#pragma unroll
    for (int nf = 0; nf < 4; ++nf)
#pragma unroll
        for (int q = 0; q < 4; ++q) {
            float v = acc[nf][q] + accL[nf][q] * INV_LO_SCALE;
            outp[(size_t)(row0 + g * 4 + q) * NE + nf * 16 + r] = v;
        }
}

// ---------------- router: sum partials, softmax + top-8 + L1 renorm ---------
// NOTE: scores aliases p0 and logits aliases p1 — each wave reads only its own
// token row before writing it; rows are wave-exclusive, so this is race-free.
__global__ __launch_bounds__(256, 1)
void router_kernel(const float* p0, const float* p1, float* scores,
                   float* logits, float* wts, float* inds, int N)
{
    const int token = blockIdx.x * 4 + (threadIdx.x >> 6);
    const int lane  = threadIdx.x & 63;
    if (token >= N) return;

    const float l = p0[(size_t)token * NE + lane] + p1[(size_t)token * NE + lane];

    float m = l;
#pragma unroll
    for (int off = 32; off >= 1; off >>= 1)
        m = fmaxf(m, __shfl_xor(m, off, 64));
    const float p = expf(l - m);
    float s = p;
#pragma unroll
    for (int off = 32; off >= 1; off >>= 1)
        s += __shfl_xor(s, off, 64);
    const float sc = p / s;

    scores[(size_t)token * NE + lane] = sc;
    logits[(size_t)token * NE + lane] = l;

    float cur = sc;
    float tv[TOPK];
    int   ti[TOPK];
    float sum8 = 0.0f;
#pragma unroll
    for (int k = 0; k < TOPK; ++k) {
        float v = cur; int i = lane;
#pragma unroll
        for (int off = 32; off >= 1; off >>= 1) {
            float ov = __shfl_xor(v, off, 64);
            int   oi = __shfl_xor(i, off, 64);
            if (ov > v || (ov == v && oi < i)) { v = ov; i = oi; }
        }
        tv[k] = v; ti[k] = i;
        sum8 += v;
        if (lane == i) cur = -1.0f;   // scores > 0, so -1 masks
    }

    if (lane == 0) {
#pragma unroll
        for (int k = 0; k < TOPK; ++k) {
            wts[(size_t)token * TOPK + k]  = tv[k] / sum8;
            inds[(size_t)token * TOPK + k] = (float)ti[k];
        }
    }
}

extern "C" void kernel_launch(void* const* d_in, const int* in_sizes, int n_in,
                              void* d_out, int out_size, void* d_ws, size_t ws_size,
                              hipStream_t stream)
{
    const float* x = (const float*)d_in[0];
    const float* W = (const float*)d_in[1];
    const int N = in_sizes[0] / H_DIM;   // 16384

    float* out    = (float*)d_out;
    float* scores = out;                          // [N,64]  (doubles as partial kh=0)
    float* logits = out + (size_t)N * NE;         // [N,64]  (doubles as partial kh=1)
    float* wts    = out + (size_t)2 * N * NE;     // [N,8]
    float* inds   = wts + (size_t)N * TOPK;       // [N,8] as float

    _Float16* pk = (_Float16*)d_ws;               // 2 * 262144 * 2B = 1 MB

    pack_w_kernel<<<(NE * H_DIM) / 256, 256, 0, stream>>>(W, pk);
    moe_logits_mfma<<<(N / 64) * 2, 256, 0, stream>>>(x, pk, scores, logits);
    router_kernel<<<(N + 3) / 4, 256, 0, stream>>>(scores, logits, scores, logits,
                                                   wts, inds, N);
}